// Round 1
// baseline (241.699 us; speedup 1.0000x reference)
//
#include <hip/hip_runtime.h>
#include <hip/hip_bf16.h>
#include <stdint.h>

#define E_ 768
#define H_ 768
#define C_ 9
#define M_TOTAL 32768

typedef __attribute__((ext_vector_type(8))) __bf16 bf16x8;
typedef __attribute__((ext_vector_type(4))) float f32x4;
typedef __attribute__((ext_vector_type(4))) int i32x4;

static_assert(sizeof(bf16x8) == 16, "bf16x8 must be 16B");

__device__ __forceinline__ unsigned short f2bf(float f) {
    __hip_bfloat16 h = __float2bfloat16(f);
    return __builtin_bit_cast(unsigned short, h);
}

// ---------------------------------------------------------------------------
// Prep: repack W1 (fp32 [E][H]) into bf16 MFMA-B fragment cells:
//   W1f[((ntile*24 + t)*64 + lane)*8 + j] = bf16(W1[k][n])
//     n = ntile*16 + (lane&15), k = t*32 + (lane>>4)*8 + j
// and W2 (fp32 [H][C]) into bf16 B-fragment cells padded to 16 cols:
//   W2f[((t*64)+lane)*8 + j] = bf16(W2[k][cls]) or 0 for cls>=9
// Also zero the loss accumulator (d_out is poisoned before every launch).
// ---------------------------------------------------------------------------
__global__ void prep_kernel(const float* __restrict__ W1, const float* __restrict__ W2,
                            unsigned short* __restrict__ W1f, unsigned short* __restrict__ W2f,
                            float* __restrict__ loss_out)
{
    int tid = blockIdx.x * 256 + threadIdx.x;
    if (tid < 48 * 24 * 512) {
        int j    = tid & 7;
        int lane = (tid >> 3) & 63;
        int cell = tid >> 9;          // ntile*24 + t
        int t     = cell % 24;
        int ntile = cell / 24;
        int n = ntile * 16 + (lane & 15);
        int k = t * 32 + (lane >> 4) * 8 + j;
        W1f[tid] = f2bf(W1[k * H_ + n]);
    }
    if (tid < 24 * 512) {
        int j    = tid & 7;
        int lane = (tid >> 3) & 63;
        int t    = tid >> 9;
        int cls  = lane & 15;
        int k = t * 32 + (lane >> 4) * 8 + j;
        W2f[tid] = (cls < C_) ? f2bf(W2[k * C_ + cls]) : (unsigned short)0;
    }
    if (tid == 0) *loss_out = 0.0f;
}

// ---------------------------------------------------------------------------
// Fused head kernel. Block = 64 tokens x full H=768. 4 waves.
//   - A (hidden) fp32 -> bf16 fragment cells in LDS, staged once (96 KB).
//   - B fragments are wave-private -> loaded straight from W1f (global/L2).
//   - 3 N-chunks of 256: K-loop (24 x BK32, 16 MFMA/step/wave, barrier-free),
//     tanh epilogue, h -> LDS (A-frag layout), 8 logit MFMAs vs W2f,
//     then shuffle softmax + probs store + loss atomic.
// ---------------------------------------------------------------------------
__launch_bounds__(256, 1)
__global__ void fused_head_kernel(const float* __restrict__ hidden,
                                  const unsigned short* __restrict__ W1f,
                                  const float* __restrict__ b1,
                                  const unsigned short* __restrict__ W2f,
                                  const float* __restrict__ b2,
                                  const int* __restrict__ labels,
                                  const int* __restrict__ epoch_p,
                                  float* __restrict__ probs,
                                  float* __restrict__ loss)
{
    __shared__ unsigned short Ash[4 * 24 * 64 * 8];   // 96 KB: A frag cells [mt][t][lane][8]
    __shared__ unsigned short Hsh[8 * 4 * 64 * 8];    // 32 KB: h frag cells [t2][mt][lane][8]

    const int tid  = threadIdx.x;
    const int w    = tid >> 6;     // wave 0..3
    const int lane = tid & 63;
    const int tok0 = blockIdx.x * 64;
    const int c16  = lane & 15;
    const int q    = lane >> 4;

    // ---- stage A: hidden[tok0..tok0+63][0..767] fp32 -> bf16 frag cells ----
#pragma unroll
    for (int i = 0; i < 24; ++i) {
        int cid  = i * 256 + tid;       // cell-slot id 0..6143
        int cl   = cid & 63;            // fragment lane
        int cell = cid >> 6;            // mt*24 + t
        int t  = cell % 24;
        int mt = cell / 24;
        int row = tok0 + mt * 16 + (cl & 15);
        int k   = t * 32 + (cl >> 4) * 8;
        const float4* gp = (const float4*)(hidden + (size_t)row * E_ + k);
        float4 v0 = gp[0];
        float4 v1 = gp[1];
        union { unsigned short u[8]; i32x4 v; } pk;
        pk.u[0] = f2bf(v0.x); pk.u[1] = f2bf(v0.y);
        pk.u[2] = f2bf(v0.z); pk.u[3] = f2bf(v0.w);
        pk.u[4] = f2bf(v1.x); pk.u[5] = f2bf(v1.y);
        pk.u[6] = f2bf(v1.z); pk.u[7] = f2bf(v1.w);
        *(i32x4*)(&Ash[cid * 8]) = pk.v;
    }
    __syncthreads();

    const f32x4 zero4 = {0.0f, 0.0f, 0.0f, 0.0f};
    f32x4 logit = zero4;   // wave w accumulates logits for rows w*16..w*16+15

    for (int c = 0; c < 3; ++c) {          // N-chunks of 256 cols
        f32x4 acc[4][4];
#pragma unroll
        for (int mt = 0; mt < 4; ++mt)
#pragma unroll
            for (int nt = 0; nt < 4; ++nt)
                acc[mt][nt] = zero4;

        const unsigned short* bbase[4];
#pragma unroll
        for (int nt = 0; nt < 4; ++nt) {
            int ntile = c * 16 + w * 4 + nt;           // wave-private n-tiles
            bbase[nt] = W1f + ((size_t)ntile * 24 * 64 + lane) * 8;
        }

        // ---- K loop: 24 steps of BK=32, no barriers ----
#pragma unroll 4
        for (int t = 0; t < 24; ++t) {
            bf16x8 bfr[4], af[4];
#pragma unroll
            for (int nt = 0; nt < 4; ++nt)
                bfr[nt] = __builtin_bit_cast(bf16x8, *(const i32x4*)(bbase[nt] + t * 512));
#pragma unroll
            for (int mt = 0; mt < 4; ++mt)
                af[mt] = __builtin_bit_cast(bf16x8, *(const i32x4*)(&Ash[((mt * 24 + t) * 64 + lane) * 8]));
#pragma unroll
            for (int mt = 0; mt < 4; ++mt)
#pragma unroll
                for (int nt = 0; nt < 4; ++nt)
                    acc[mt][nt] = __builtin_amdgcn_mfma_f32_16x16x32_bf16(af[mt], bfr[nt], acc[mt][nt], 0, 0, 0);
        }

        // ---- epilogue: +b1, tanh, write h into Hsh in A-fragment layout ----
        // C/D layout: col = c16 (within 16-tile), row = q*4 + r (within 16-tile)
#pragma unroll
        for (int nt = 0; nt < 4; ++nt) {
            int colg = c * 256 + w * 64 + nt * 16 + c16;   // global h-col
            float b1v = b1[colg];
            int kloc = w * 64 + nt * 16 + c16;             // chunk-local k of h
            int t2 = kloc >> 5;                            // in {2w, 2w+1}: wave-private
            int q2 = (kloc >> 3) & 3;
            int j  = kloc & 7;
#pragma unroll
            for (int mt = 0; mt < 4; ++mt) {
#pragma unroll
                for (int r = 0; r < 4; ++r) {
                    float z = acc[mt][nt][r] + b1v;
                    // tanh(z) = 1 - 2/(exp(2z)+1), exp via native exp2
                    float e = exp2f(z * 2.8853900817779268f);
                    float th = 1.0f - 2.0f * __builtin_amdgcn_rcpf(e + 1.0f);
                    int lanep = (q * 4 + r) + 16 * q2;     // frag lane for row (mt*16 + q*4+r)
                    Hsh[((t2 * 4 + mt) * 64 + lanep) * 8 + j] = f2bf(th);
                }
            }
        }
        __syncthreads();   // h visible to all waves

        // ---- logit MFMAs: wave w does rows w*16..+15, K = this chunk's 256 cols ----
#pragma unroll
        for (int t2 = 0; t2 < 8; ++t2) {
            bf16x8 ha = __builtin_bit_cast(bf16x8, *(const i32x4*)(&Hsh[((t2 * 4 + w) * 64 + lane) * 8]));
            bf16x8 wb = __builtin_bit_cast(bf16x8, *(const i32x4*)(W2f + ((size_t)(c * 8 + t2) * 64 + lane) * 8));
            logit = __builtin_amdgcn_mfma_f32_16x16x32_bf16(ha, wb, logit, 0, 0, 0);
        }
        __syncthreads();   // all logit reads done before next chunk rewrites Hsh
    }

    // ---- softmax over 9 classes (16-lane groups), probs store, loss ----
    const bool valid = (c16 < C_);
    const float b2v = valid ? b2[c16] : 0.0f;
    const int ep = epoch_p[0];
    float lsum = 0.0f;
#pragma unroll
    for (int r = 0; r < 4; ++r) {
        float l = valid ? (logit[r] + b2v) : -3.0e38f;
        float m = l;
#pragma unroll
        for (int d = 1; d < 16; d <<= 1)
            m = fmaxf(m, __shfl_xor(m, d, 64));
        float e = valid ? exp2f((l - m) * 1.44269504f) : 0.0f;
        float s = e;
#pragma unroll
        for (int d = 1; d < 16; d <<= 1)
            s += __shfl_xor(s, d, 64);
        float p = e / s;
        int row = tok0 + w * 16 + q * 4 + r;
        if (valid) probs[(size_t)row * C_ + c16] = p;
        int lab = labels[row];
        if (valid && lab == c16) {
            float wgt = (ep <= 2) ? 1.0f : ((p > 0.7f) ? 1.0f : 0.0f);
            if (wgt > 0.0f)
                lsum += (1.0f - exp2f(0.7f * log2f(p))) * (1.0f / 0.7f);
        }
    }
#pragma unroll
    for (int d = 1; d < 64; d <<= 1)
        lsum += __shfl_xor(lsum, d, 64);
    if (lane == 0) atomicAdd(loss, lsum);
}

// ---------------------------------------------------------------------------
extern "C" void kernel_launch(void* const* d_in, const int* in_sizes, int n_in,
                              void* d_out, int out_size, void* d_ws, size_t ws_size,
                              hipStream_t stream)
{
    const float* hidden = (const float*)d_in[0];
    const float* W1     = (const float*)d_in[1];
    const float* b1     = (const float*)d_in[2];
    const float* W2     = (const float*)d_in[3];
    const float* b2     = (const float*)d_in[4];
    const int*   labels = (const int*)d_in[5];
    const int*   epoch  = (const int*)d_in[6];

    float* probs = (float*)d_out;                       // [32768 x 9]
    float* loss  = probs + (size_t)M_TOTAL * C_;        // scalar at the end

    unsigned short* W1f = (unsigned short*)d_ws;        // 589824 bf16
    unsigned short* W2f = W1f + 48 * 24 * 512;          // 12288 bf16

    prep_kernel<<<2304, 256, 0, stream>>>(W1, W2, W1f, W2f, loss);
    fused_head_kernel<<<512, 256, 0, stream>>>(hidden, W1f, b1, W2f, b2,
                                               labels, epoch, probs, loss);
}

// Round 2
// 232.707 us; speedup vs baseline: 1.0386x; 1.0386x over previous
//
#include <hip/hip_runtime.h>
#include <hip/hip_bf16.h>
#include <stdint.h>

#define E_ 768
#define H_ 768
#define C_ 9
#define M_TOTAL 32768

typedef __attribute__((ext_vector_type(8))) __bf16 bf16x8;
typedef __attribute__((ext_vector_type(4))) float f32x4;
typedef __attribute__((ext_vector_type(4))) int i32x4;

static_assert(sizeof(bf16x8) == 16, "bf16x8 must be 16B");

__device__ __forceinline__ unsigned short f2bf(float f) {
    __hip_bfloat16 h = __float2bfloat16(f);
    return __builtin_bit_cast(unsigned short, h);
}

// ---------------------------------------------------------------------------
// Prep: repack W1 (fp32 [E][H]) into bf16 MFMA-B fragment cells:
//   W1f[((ntile*24 + t)*64 + lane)*8 + j] = bf16(W1[k][n])
//     n = ntile*16 + (lane&15), k = t*32 + (lane>>4)*8 + j
// and W2 (fp32 [H][C]) into bf16 B-fragment cells padded to 16 cols.
// Also zero the loss accumulator (d_out is poisoned before every launch).
// ---------------------------------------------------------------------------
__global__ void prep_kernel(const float* __restrict__ W1, const float* __restrict__ W2,
                            unsigned short* __restrict__ W1f, unsigned short* __restrict__ W2f,
                            float* __restrict__ loss_out)
{
    int tid = blockIdx.x * 256 + threadIdx.x;
    if (tid < 48 * 24 * 512) {
        int j    = tid & 7;
        int lane = (tid >> 3) & 63;
        int cell = tid >> 9;          // ntile*24 + t
        int t     = cell % 24;
        int ntile = cell / 24;
        int n = ntile * 16 + (lane & 15);
        int k = t * 32 + (lane >> 4) * 8 + j;
        W1f[tid] = f2bf(W1[k * H_ + n]);
    }
    if (tid < 24 * 512) {
        int j    = tid & 7;
        int lane = (tid >> 3) & 63;
        int t    = tid >> 9;
        int cls  = lane & 15;
        int k = t * 32 + (lane >> 4) * 8 + j;
        W2f[tid] = (cls < C_) ? f2bf(W2[k * C_ + cls]) : (unsigned short)0;
    }
    if (tid == 0) *loss_out = 0.0f;
}

// ---------------------------------------------------------------------------
// Fused head kernel. Block = 64 tokens x full H=768. 8 waves (512 thr):
// 2 waves/SIMD for latency hiding (round-1 had 1 wave/SIMD, MfmaUtil 12.7%).
//   - A (hidden) fp32 -> bf16 fragment cells in LDS, staged once (96 KB).
//   - B fragments wave-private (2 n-tiles/wave) -> loaded straight from W1f.
//   - 3 N-chunks of 256: barrier-free K-loop (24 x BK32, 8 MFMA/step/wave),
//     tanh epilogue, h -> LDS (A-frag layout), logit MFMAs on waves 0-3,
//     then shuffle softmax + probs store + loss atomic.
// ---------------------------------------------------------------------------
__launch_bounds__(512, 2)
__global__ void fused_head_kernel(const float* __restrict__ hidden,
                                  const unsigned short* __restrict__ W1f,
                                  const float* __restrict__ b1,
                                  const unsigned short* __restrict__ W2f,
                                  const float* __restrict__ b2,
                                  const int* __restrict__ labels,
                                  const int* __restrict__ epoch_p,
                                  float* __restrict__ probs,
                                  float* __restrict__ loss)
{
    __shared__ unsigned short Ash[4 * 24 * 64 * 8];   // 96 KB: A frag cells [mt][t][lane][8]
    __shared__ unsigned short Hsh[8 * 4 * 64 * 8];    // 32 KB: h frag cells [t2][mt][lane][8]

    const int tid  = threadIdx.x;
    const int w    = tid >> 6;     // wave 0..7
    const int lane = tid & 63;
    const int tok0 = blockIdx.x * 64;
    const int c16  = lane & 15;
    const int q    = lane >> 4;

    // ---- stage A: hidden[tok0..tok0+63][0..767] fp32 -> bf16 frag cells ----
#pragma unroll
    for (int i = 0; i < 12; ++i) {
        int cid  = i * 512 + tid;       // cell-slot id 0..6143
        int cl   = cid & 63;            // fragment lane
        int cell = cid >> 6;            // mt*24 + t
        int t  = cell % 24;
        int mt = cell / 24;
        int row = tok0 + mt * 16 + (cl & 15);
        int k   = t * 32 + (cl >> 4) * 8;
        const float4* gp = (const float4*)(hidden + (size_t)row * E_ + k);
        float4 v0 = gp[0];
        float4 v1 = gp[1];
        union { unsigned short u[8]; i32x4 v; } pk;
        pk.u[0] = f2bf(v0.x); pk.u[1] = f2bf(v0.y);
        pk.u[2] = f2bf(v0.z); pk.u[3] = f2bf(v0.w);
        pk.u[4] = f2bf(v1.x); pk.u[5] = f2bf(v1.y);
        pk.u[6] = f2bf(v1.z); pk.u[7] = f2bf(v1.w);
        *(i32x4*)(&Ash[cid * 8]) = pk.v;
    }
    __syncthreads();

    const f32x4 zero4 = {0.0f, 0.0f, 0.0f, 0.0f};
    f32x4 logit = zero4;   // waves 0-3: wave w accumulates logits for rows w*16..+15

    for (int c = 0; c < 3; ++c) {          // N-chunks of 256 cols
        f32x4 acc[4][2];
#pragma unroll
        for (int mt = 0; mt < 4; ++mt)
#pragma unroll
            for (int nt = 0; nt < 2; ++nt)
                acc[mt][nt] = zero4;

        const unsigned short* bbase[2];
#pragma unroll
        for (int nt = 0; nt < 2; ++nt) {
            int ntile = c * 16 + w * 2 + nt;           // wave-private n-tiles
            bbase[nt] = W1f + ((size_t)ntile * 24 * 64 + lane) * 8;
        }

        // ---- K loop: 24 steps of BK=32, no barriers ----
#pragma unroll 8
        for (int t = 0; t < 24; ++t) {
            bf16x8 bfr[2], af[4];
#pragma unroll
            for (int nt = 0; nt < 2; ++nt)
                bfr[nt] = __builtin_bit_cast(bf16x8, *(const i32x4*)(bbase[nt] + t * 512));
#pragma unroll
            for (int mt = 0; mt < 4; ++mt)
                af[mt] = __builtin_bit_cast(bf16x8, *(const i32x4*)(&Ash[((mt * 24 + t) * 64 + lane) * 8]));
#pragma unroll
            for (int mt = 0; mt < 4; ++mt)
#pragma unroll
                for (int nt = 0; nt < 2; ++nt)
                    acc[mt][nt] = __builtin_amdgcn_mfma_f32_16x16x32_bf16(af[mt], bfr[nt], acc[mt][nt], 0, 0, 0);
        }

        // ---- epilogue: +b1, tanh, write h into Hsh in A-fragment layout ----
        // C/D layout: col = c16 (within 16-tile), row = q*4 + r (within 16-tile)
#pragma unroll
        for (int nt = 0; nt < 2; ++nt) {
            int kloc = w * 32 + nt * 16 + c16;             // chunk-local k of h (0..255)
            int colg = c * 256 + kloc;                     // global h-col
            float b1v = b1[colg];
            int t2 = kloc >> 5;                            // == w: wave-private
            int q2 = (kloc >> 3) & 3;
            int j  = kloc & 7;
#pragma unroll
            for (int mt = 0; mt < 4; ++mt) {
#pragma unroll
                for (int r = 0; r < 4; ++r) {
                    float z = acc[mt][nt][r] + b1v;
                    // tanh(z) = 1 - 2/(exp(2z)+1), exp via native exp2
                    float e = exp2f(z * 2.8853900817779268f);
                    float th = 1.0f - 2.0f * __builtin_amdgcn_rcpf(e + 1.0f);
                    int lanep = (q * 4 + r) + 16 * q2;     // frag lane for row (mt*16 + q*4+r)
                    Hsh[((t2 * 4 + mt) * 64 + lanep) * 8 + j] = f2bf(th);
                }
            }
        }
        __syncthreads();   // h visible to all waves

        // ---- logit MFMAs: waves 0-3 only; wave w does rows w*16..+15 ----
        if (w < 4) {
#pragma unroll
            for (int t2 = 0; t2 < 8; ++t2) {
                bf16x8 ha = __builtin_bit_cast(bf16x8, *(const i32x4*)(&Hsh[((t2 * 4 + w) * 64 + lane) * 8]));
                bf16x8 wb = __builtin_bit_cast(bf16x8, *(const i32x4*)(W2f + ((size_t)(c * 8 + t2) * 64 + lane) * 8));
                logit = __builtin_amdgcn_mfma_f32_16x16x32_bf16(ha, wb, logit, 0, 0, 0);
            }
        }
        __syncthreads();   // all logit reads done before next chunk rewrites Hsh
    }

    // ---- softmax over 9 classes (16-lane groups), probs store, loss ----
    if (w < 4) {
        const bool valid = (c16 < C_);
        const float b2v = valid ? b2[c16] : 0.0f;
        const int ep = epoch_p[0];
        float lsum = 0.0f;
#pragma unroll
        for (int r = 0; r < 4; ++r) {
            float l = valid ? (logit[r] + b2v) : -3.0e38f;
            float m = l;
#pragma unroll
            for (int d = 1; d < 16; d <<= 1)
                m = fmaxf(m, __shfl_xor(m, d, 64));
            float e = valid ? exp2f((l - m) * 1.44269504f) : 0.0f;
            float s = e;
#pragma unroll
            for (int d = 1; d < 16; d <<= 1)
                s += __shfl_xor(s, d, 64);
            float p = e / s;
            int row = tok0 + w * 16 + q * 4 + r;
            if (valid) probs[(size_t)row * C_ + c16] = p;
            int lab = labels[row];
            if (valid && lab == c16) {
                float wgt = (ep <= 2) ? 1.0f : ((p > 0.7f) ? 1.0f : 0.0f);
                if (wgt > 0.0f)
                    lsum += (1.0f - exp2f(0.7f * log2f(p))) * (1.0f / 0.7f);
            }
        }
#pragma unroll
        for (int d = 1; d < 64; d <<= 1)
            lsum += __shfl_xor(lsum, d, 64);
        if (lane == 0) atomicAdd(loss, lsum);
    }
}

// ---------------------------------------------------------------------------
extern "C" void kernel_launch(void* const* d_in, const int* in_sizes, int n_in,
                              void* d_out, int out_size, void* d_ws, size_t ws_size,
                              hipStream_t stream)
{
    const float* hidden = (const float*)d_in[0];
    const float* W1     = (const float*)d_in[1];
    const float* b1     = (const float*)d_in[2];
    const float* W2     = (const float*)d_in[3];
    const float* b2     = (const float*)d_in[4];
    const int*   labels = (const int*)d_in[5];
    const int*   epoch  = (const int*)d_in[6];

    float* probs = (float*)d_out;                       // [32768 x 9]
    float* loss  = probs + (size_t)M_TOTAL * C_;        // scalar at the end

    unsigned short* W1f = (unsigned short*)d_ws;        // 589824 bf16
    unsigned short* W2f = W1f + 48 * 24 * 512;          // 12288 bf16

    prep_kernel<<<2304, 256, 0, stream>>>(W1, W2, W1f, W2f, loss);
    fused_head_kernel<<<512, 512, 0, stream>>>(hidden, W1f, b1, W2f, b2,
                                               labels, epoch, probs, loss);
}